// Round 14
// baseline (235.051 us; speedup 1.0000x reference)
//
#include <hip/hip_runtime.h>
#include <array>

#define DEV_INLINE __device__ __forceinline__

// Problem geometry (fixed by setup_inputs)
constexpr int HH = 512, WW = 512, BB = 4;
constexpr int HWN = HH * WW;
constexpr int NPX = BB * HWN;           // 1,048,576 pixels
constexpr int OUT1OFF = NPX * 9;        // d_out: [B*HW*9] then [B*HW*13]

// ---------------------------------------------------------------------------
// Compile-time sparse structure of the real Wigner-3j tensors.
// ---------------------------------------------------------------------------
constexpr bool keepE(int u1, int u2, int u3) {
    int a = u1 < 0 ? -u1 : u1, b = u2 < 0 ? -u2 : u2, c = u3 < 0 ? -u3 : u3;
    int neg = (u1 < 0) + (u2 < 0) + (u3 < 0);
    if (neg & 1) return false;
    int d = a > b ? a - b : b - a;
    return (c == a + b) || (c == d);
}

struct Ent { unsigned char xi, yi, oi, p; };

// Group order: (4,4), (6,4), (4,6), (6,6)
constexpr int GRP[4][2] = {{4,4},{6,4},{4,6},{6,6}};

constexpr int countEnt() {
    int n = 0;
    for (int g = 0; g < 4; ++g) {
        int l1 = GRP[g][0], l2 = GRP[g][1];
        for (int u1 = -l1; u1 <= l1; ++u1)
            for (int u2 = -l2; u2 <= l2; ++u2)
                for (int t3 = 0; t3 < 2; ++t3) {
                    int l3 = t3 ? 6 : 4;
                    for (int u3 = -l3; u3 <= l3; ++u3)
                        if (keepE(u1, u2, u3)) ++n;
                }
    }
    return n;
}
constexpr int NTOT = countEnt();
static_assert(NTOT > 0 && NTOT < 4096, "entry count sanity");

constexpr std::array<Ent, NTOT> makeTab() {
    std::array<Ent, NTOT> T{};
    int n = 0;
    for (int g = 0; g < 4; ++g) {
        int l1 = GRP[g][0], l2 = GRP[g][1];
        int xo = (l1 == 6) ? 9 : 0, yo = (l2 == 6) ? 9 : 0;
        for (int u1 = -l1; u1 <= l1; ++u1)
            for (int u2 = -l2; u2 <= l2; ++u2)
                for (int t3 = 0; t3 < 2; ++t3) {
                    int l3 = t3 ? 6 : 4;
                    int oo = (l3 == 6) ? 9 : 0;
                    for (int u3 = -l3; u3 <= l3; ++u3)
                        if (keepE(u1, u2, u3)) {
                            T[n].xi = (unsigned char)(xo + l1 + u1);
                            T[n].yi = (unsigned char)(yo + l2 + u2);
                            T[n].oi = (unsigned char)(oo + l3 + u3);
                            T[n].p  = (unsigned char)(((l1 == 6) ? 4 : 0) |
                                                      ((l2 == 6) ? 2 : 0) |
                                                      ((l3 == 6) ? 1 : 0));
                            ++n;
                        }
                }
    }
    return T;
}
constexpr auto TAB = makeTab();

struct Run { unsigned short e0; unsigned char xi, yi, n; };

constexpr int countRuns() {
    int n = 0;
    for (int e = 0; e < NTOT; ) {
        int j = e;
        while (j < NTOT && TAB[j].xi == TAB[e].xi && TAB[j].yi == TAB[e].yi) ++j;
        ++n; e = j;
    }
    return n;
}
constexpr int NRUN = countRuns();

constexpr std::array<Run, NRUN> makeRuns() {
    std::array<Run, NRUN> R{};
    int n = 0;
    for (int e = 0; e < NTOT; ) {
        int j = e;
        while (j < NTOT && TAB[j].xi == TAB[e].xi && TAB[j].yi == TAB[e].yi) ++j;
        R[n].e0 = (unsigned short)e;
        R[n].xi = TAB[e].xi;
        R[n].yi = TAB[e].yi;
        R[n].n  = (unsigned char)(j - e);
        ++n; e = j;
    }
    return R;
}
constexpr auto RUNS = makeRuns();

constexpr int grpPos(int pp) { return pp == 0 ? 0 : (pp == 2 ? 1 : (pp == 1 ? 2 : 3)); }
constexpr std::array<int, 5> makeGB() {
    std::array<int, 5> G{};
    G[0] = 0;
    int g = 0;
    for (int r = 0; r < NRUN; ++r) {
        int gp = grpPos(TAB[RUNS[r].e0].p >> 1);
        while (g < gp) { ++g; G[g] = r; }
    }
    while (g < 4) { ++g; G[g] = NRUN; }
    G[4] = NRUN;
    return G;
}
constexpr auto GB = makeGB();
static_assert(GB[4] == NRUN, "GB sanity");

// Per-run / per-entry output-selection helpers (SEL=0 -> o4, SEL=1 -> o6).
constexpr bool entSel(int e, int SEL) {
    return SEL ? (TAB[e].oi >= 9) : (TAB[e].oi < 9);
}
constexpr int runCount(int r, int SEL) {
    int c = 0;
    for (int e = RUNS[r].e0; e < RUNS[r].e0 + RUNS[r].n; ++e)
        if (entSel(e, SEL)) ++c;
    return c;
}

// ---------------------------------------------------------------------------
// Compile-time Wigner-3j values (fp64 constexpr, Newton csqrt).
// ---------------------------------------------------------------------------
constexpr std::array<double, 20> makeFact() {
    std::array<double, 20> F{};
    F[0] = 1.0;
    for (int i = 1; i < 20; ++i) F[i] = F[i - 1] * (double)i;
    return F;
}
constexpr auto FACT = makeFact();

constexpr double csqrt(double x) {
    if (x <= 0.0) return 0.0;
    double g = x > 1.0 ? x : 1.0, prev = 0.0;
    for (int i = 0; i < 200 && g != prev; ++i) { prev = g; g = 0.5 * (g + x / g); }
    return g;
}

constexpr double su2cg(int j1, int j2, int j3, int m1, int m2, int m3) {
    int vmin = -j1 + j2 + m3;
    if (-j1 + m1 > vmin) vmin = -j1 + m1;
    if (vmin < 0) vmin = 0;
    int vmax = j2 + j3 + m1;
    { int t = j3 - j1 + j2; if (t < vmax) vmax = t; t = j3 + m3; if (t < vmax) vmax = t; }
    double num = FACT[j3 + j1 - j2] * FACT[j3 - j1 + j2] * FACT[j1 + j2 - j3] *
                 FACT[j3 + m3] * FACT[j3 - m3];
    double den = FACT[j1 + j2 + j3 + 1] * FACT[j1 - m1] * FACT[j1 + m1] *
                 FACT[j2 - m2] * FACT[j2 + m2];
    double C = csqrt((2.0 * j3 + 1.0) * num / den);
    double S = 0.0;
    for (int v = vmin; v <= vmax; ++v) {
        double t = (FACT[j2 + j3 + m1 - v] * FACT[j1 - m1 + v]) /
                   (FACT[v] * FACT[j3 - j1 + j2 - v] * FACT[j3 + m3 - v] *
                    FACT[v + j1 - j2 - m3]);
        S += ((v + j2 + m2) & 1) ? -t : t;
    }
    return C * S;
}

struct Cplx { double re, im; };

constexpr Cplx qent(int l, int r, int c) {
    const double s2 = 0.70710678118654752440;
    if (c == r) {
        if (r < l)  return {0.0, -s2};
        if (r == l) return {1.0, 0.0};
        return {((r - l) & 1) ? -s2 : s2, 0.0};
    }
    if (r < l) return {s2, 0.0};
    return {0.0, ((r - l) & 1) ? -s2 : s2};
}

constexpr double rawval(int e) {
    Ent E = TAB[e];
    int l1 = (E.p & 4) ? 6 : 4, l2 = (E.p & 2) ? 6 : 4, l3 = (E.p & 1) ? 6 : 4;
    int j = E.xi - ((l1 == 6) ? 9 : 0);
    int L = E.yi - ((l2 == 6) ? 9 : 0);
    int m = E.oi - ((l3 == 6) ? 9 : 0);
    double acc = 0.0;
    for (int a = 0; a < 2; ++a) {
        int i = a ? (2 * l1 - j) : j;
        if (a && i == j) continue;
        Cplx q1 = qent(l1, i, j);
        for (int b = 0; b < 2; ++b) {
            int k = b ? (2 * l2 - L) : L;
            if (b && k == L) continue;
            Cplx q2 = qent(l2, k, L);
            int m1 = i - l1, m2 = k - l2;
            int n = m1 + m2 + l3;
            if (n < 0 || n > 2 * l3) continue;
            if (n != m && n != 2 * l3 - m) continue;
            Cplx q3 = qent(l3, n, m);
            double cg = su2cg(l1, l2, l3, m1, m2, n - l3);
            double Ar = q1.re * q2.re - q1.im * q2.im;
            double Ai = q1.re * q2.im + q1.im * q2.re;
            acc += (Ar * q3.re + Ai * q3.im) * cg;
        }
    }
    int s = 1;
    if (l1 == 6) s = -s;
    if (l2 == 6) s = -s;
    if (l3 == 6) s = -s;
    return s < 0 ? -acc : acc;
}

// Frobenius norms per path — chunked constexpr evaluations.
constexpr int NCH = 16;
constexpr int CHSZ = (NTOT + NCH - 1) / NCH;

template<int C>
constexpr std::array<double, 8> frobChunk() {
    std::array<double, 8> s{};
    for (int i = 0; i < CHSZ; ++i) {
        int e = C * CHSZ + i;
        if (e < NTOT) { double r = rawval(e); s[TAB[e].p] += r * r; }
    }
    return s;
}
constexpr auto FR0  = frobChunk<0>();   constexpr auto FR1  = frobChunk<1>();
constexpr auto FR2  = frobChunk<2>();   constexpr auto FR3  = frobChunk<3>();
constexpr auto FR4  = frobChunk<4>();   constexpr auto FR5  = frobChunk<5>();
constexpr auto FR6  = frobChunk<6>();   constexpr auto FR7  = frobChunk<7>();
constexpr auto FR8  = frobChunk<8>();   constexpr auto FR9  = frobChunk<9>();
constexpr auto FR10 = frobChunk<10>();  constexpr auto FR11 = frobChunk<11>();
constexpr auto FR12 = frobChunk<12>();  constexpr auto FR13 = frobChunk<13>();
constexpr auto FR14 = frobChunk<14>();  constexpr auto FR15 = frobChunk<15>();

constexpr std::array<double, 8> makeFrob() {
    std::array<double, 8> s{};
    const std::array<double, 8>* parts[NCH] = {
        &FR0,&FR1,&FR2,&FR3,&FR4,&FR5,&FR6,&FR7,
        &FR8,&FR9,&FR10,&FR11,&FR12,&FR13,&FR14,&FR15};
    for (int c = 0; c < NCH; ++c)
        for (int p = 0; p < 8; ++p) s[p] += (*parts[c])[p];
    for (int p = 0; p < 8; ++p) s[p] = csqrt(s[p]);
    return s;
}
constexpr auto FROB = makeFrob();

// Per-entry final coefficient — inline literal.
template<int E>
struct CofV {
    static constexpr int    P  = TAB[E].p;
    static constexpr double PW = 0.5 * ((P & 1) ? 3.60555127546398929312 /*sqrt13*/
                                               : 3.0 /*sqrt9*/);
    static constexpr float  v  = (float)(rawval(E) * PW / FROB[P]);
};

// ---------------------------------------------------------------------------
// Output-filtered force-unrolled TP (SEL=0 -> o4[9], SEL=1 -> o6[13]).
// ---------------------------------------------------------------------------
template<int E, int N, int SEL, int ON>
struct FChain {
    static DEV_INLINE void run(float pr, float (&o)[ON]) {
        if constexpr (entSel(E, SEL)) {
            constexpr int oi = SEL ? TAB[E].oi - 9 : TAB[E].oi;
            constexpr float kc = CofV<E>::v;
            o[oi] = fmaf(kc, pr, o[oi]);
        }
        if constexpr (N > 1) FChain<E + 1, N - 1, SEL, ON>::run(pr, o);
    }
};

template<int LO, int HI, int XN, int YN, int SEL, int ON>
struct TPGF {
    static DEV_INLINE void run(float s, const float (&xs)[XN],
                               const float (&ys)[YN], float (&o)[ON]) {
        if constexpr (HI - LO == 1) {
            if constexpr (runCount(LO, SEL) > 0) {
                constexpr Run R = RUNS[LO];
                constexpr int xil = R.xi >= 9 ? R.xi - 9 : R.xi;
                constexpr int yil = R.yi >= 9 ? R.yi - 9 : R.yi;
                float pr = xs[xil] * ys[yil] * s;
                FChain<R.e0, R.n, SEL, ON>::run(pr, o);
            }
        } else {
            constexpr int MID = LO + (HI - LO) / 2;
            TPGF<LO, MID, XN, YN, SEL, ON>::run(s, xs, ys, o);
            TPGF<MID, HI, XN, YN, SEL, ON>::run(s, xs, ys, o);
        }
    }
};

// One pixel's output-filtered TP (+ residual init).
template<int SEL, int ON>
DEV_INLINE void tp_one(const float (&tpws)[8],
                       const float (&xx4)[9], const float (&xx6)[13],
                       const float (&yy4)[9], const float (&yy6)[13],
                       float (&o)[ON]) {
    if constexpr (SEL == 0) {
#pragma unroll
        for (int c = 0; c < 9; ++c) o[c] = xx4[c];
    } else {
#pragma unroll
        for (int c = 0; c < 13; ++c) o[c] = xx6[c];
    }
    TPGF<GB[0], GB[1], 9, 9, SEL, ON>::run(tpws[SEL ? 1 : 0], xx4, yy4, o);
    TPGF<GB[1], GB[2], 13, 9, SEL, ON>::run(tpws[SEL ? 5 : 4], xx6, yy4, o);
    TPGF<GB[2], GB[3], 9, 13, SEL, ON>::run(tpws[SEL ? 3 : 2], xx4, yy6, o);
    TPGF<GB[3], GB[4], 13, 13, SEL, ON>::run(tpws[SEL ? 7 : 6], xx6, yy6, o);
}

// Unfiltered full TP (fused fallback only).
template<int E, int N>
struct AccChain {
    static DEV_INLINE void run(float pr4, float pr6,
                               float (&o4)[9], float (&o6)[13]) {
        constexpr int oi = TAB[E].oi;
        constexpr float kc = CofV<E>::v;
        if constexpr (oi < 9) o4[oi] = fmaf(kc, pr4, o4[oi]);
        else                  o6[oi - 9] = fmaf(kc, pr6, o6[oi - 9]);
        if constexpr (N > 1) AccChain<E + 1, N - 1>::run(pr4, pr6, o4, o6);
    }
};

template<int LO, int HI, int XN, int YN>
struct TPG {
    static DEV_INLINE void run(float s4, float s6,
                               const float (&xs)[XN], const float (&ys)[YN],
                               float (&o4)[9], float (&o6)[13]) {
        if constexpr (HI - LO == 1) {
            constexpr Run R = RUNS[LO];
            constexpr int xil = R.xi >= 9 ? R.xi - 9 : R.xi;
            constexpr int yil = R.yi >= 9 ? R.yi - 9 : R.yi;
            constexpr bool has4 = (TAB[R.e0].p & 1) == 0;
            constexpr bool has6 = (TAB[R.e0 + R.n - 1].p & 1) == 1;
            float pr = xs[xil] * ys[yil];
            float pr4 = 0.f, pr6 = 0.f;
            if constexpr (has4) pr4 = pr * s4;
            if constexpr (has6) pr6 = pr * s6;
            AccChain<R.e0, R.n>::run(pr4, pr6, o4, o6);
        } else {
            constexpr int MID = LO + (HI - LO) / 2;
            TPG<LO, MID, XN, YN>::run(s4, s6, xs, ys, o4, o6);
            TPG<MID, HI, XN, YN>::run(s4, s6, xs, ys, o4, o6);
        }
    }
};

// ---------------------------------------------------------------------------
// Kernel A: 3x3 conv -> yy planes (SoA) in d_ws. (R9 proven path.)
// ---------------------------------------------------------------------------
constexpr int RA = 596, RB = 860;

__global__ void __launch_bounds__(256)
conv_yy_kernel(const float* __restrict__ f4,
               const float* __restrict__ f6,
               const float* __restrict__ sw,
               float* __restrict__ yyws) {
    __shared__ __align__(16) float ldsA[6 * RA];
    __shared__ __align__(16) float ldsB[6 * RB];
    const int tid = threadIdx.x;
    const int b  = blockIdx.x >> 10;
    const int t  = blockIdx.x & 1023;
    const int y0 = (t >> 3) * 4;
    const int x0 = (t & 7) * 64;

    const float* f4b = f4 + (size_t)b * (HWN * 9);
    const float* f6b = f6 + (size_t)b * (HWN * 13);

    float wv[9];
#pragma unroll
    for (int k = 0; k < 9; ++k) wv[k] = sw[k];

    {
        const float4* f4v = (const float4*)f4b;
        const float4* f6v = (const float4*)f6b;
        float4* lAv = (float4*)ldsA;
        float4* lBv = (float4*)ldsB;
        const int xoA = (x0 * 9) >> 2;
        const int xoB = (x0 * 13) >> 2;
        for (int k = tid; k < 6 * (144 + 208); k += 256) {
            if (k < 6 * 144) {
                int r = k / 144, o = k - r * 144;
                int gy = y0 - 1 + r;
                gy = gy < 0 ? 0 : (gy > HH - 1 ? HH - 1 : gy);
                lAv[r * (RA / 4) + o] = f4v[(size_t)gy * 1152 + xoA + o];
            } else {
                int k2 = k - 6 * 144;
                int r = k2 / 208, o = k2 - r * 208;
                int gy = y0 - 1 + r;
                gy = gy < 0 ? 0 : (gy > HH - 1 ? HH - 1 : gy);
                lBv[r * (RB / 4) + o] = f6v[(size_t)gy * 1664 + xoB + o];
            }
        }
        for (int u2 = tid; u2 < 264; u2 += 256) {
            int side = u2 >= 132;
            int u = u2 - side * 132;
            int r = u / 22, c = u - r * 22;
            int gx = side ? (x0 + 64 > WW - 1 ? WW - 1 : x0 + 64)
                          : (x0 - 1 < 0 ? 0 : x0 - 1);
            int gy = y0 - 1 + r;
            gy = gy < 0 ? 0 : (gy > HH - 1 ? HH - 1 : gy);
            if (c < 9)
                ldsA[r * RA + (side ? 585 : 576) + c] =
                    f4b[(size_t)gy * 4608 + gx * 9 + c];
            else
                ldsB[r * RB + (side ? 845 : 832) + (c - 9)] =
                    f6b[(size_t)gy * 6656 + gx * 13 + (c - 9)];
        }
    }
    __syncthreads();

    const int tx = tid & 63, ty = tid >> 6;

    const int aLA = (tx == 0) ? 576 : (tx - 1) * 9;
    const int aMA = tx * 9;
    const int aRA_ = (tx == 63) ? 585 : (tx + 1) * 9;
    const int aLB = (tx == 0) ? 832 : (tx - 1) * 13;
    const int aMB = tx * 13;
    const int aRB_ = (tx == 63) ? 845 : (tx + 1) * 13;

    const float* pAL = ldsA + ty * RA + aLA;
    const float* pAM = ldsA + ty * RA + aMA;
    const float* pAR = ldsA + ty * RA + aRA_;
    const float* pBL = ldsB + ty * RB + aLB;
    const float* pBM = ldsB + ty * RB + aMB;
    const float* pBR = ldsB + ty * RB + aRB_;

    const int pos = b * HWN + (y0 + ty) * WW + (x0 + tx);

#pragma unroll
    for (int c = 0; c < 9; ++c) {
        float s = 0.f;
#pragma unroll
        for (int jr = 0; jr < 3; ++jr) {
            s = fmaf(wv[jr * 3 + 0], pAL[jr * RA + c], s);
            s = fmaf(wv[jr * 3 + 1], pAM[jr * RA + c], s);
            s = fmaf(wv[jr * 3 + 2], pAR[jr * RA + c], s);
        }
        yyws[(size_t)c * NPX + pos] = s;
    }
#pragma unroll
    for (int c = 0; c < 13; ++c) {
        float s = 0.f;
#pragma unroll
        for (int jr = 0; jr < 3; ++jr) {
            s = fmaf(wv[jr * 3 + 0], pBL[jr * RB + c], s);
            s = fmaf(wv[jr * 3 + 1], pBM[jr * RB + c], s);
            s = fmaf(wv[jr * 3 + 2], pBR[jr * RB + c], s);
        }
        yyws[(size_t)(9 + c) * NPX + pos] = s;
    }
}

// ---------------------------------------------------------------------------
// Kernel K1: o4 only, 2 px/thread (A/B independent streams).
// ---------------------------------------------------------------------------
__global__ void __launch_bounds__(256)
tp_o4_kernel(const float* __restrict__ f4,
             const float* __restrict__ f6,
             const float* __restrict__ yyws,
             const float* __restrict__ tpw,
             float* __restrict__ dout) {
    __shared__ float lds[512 * 9];
    const int tid = threadIdx.x;
    const int gid = blockIdx.x * 256 + tid;     // pixel-pair index
    const int pxA = gid * 2;

    float tpws[8];
#pragma unroll
    for (int k = 0; k < 8; ++k) tpws[k] = tpw[k];

    float xx4A[9], xx4B[9], xx6A[13], xx6B[13];
    float yy4A[9], yy4B[9], yy6A[13], yy6B[13];
#pragma unroll
    for (int c = 0; c < 9; ++c) {
        xx4A[c] = f4[(size_t)pxA * 9 + c];
        xx4B[c] = f4[(size_t)pxA * 9 + 9 + c];
    }
#pragma unroll
    for (int c = 0; c < 13; ++c) {
        xx6A[c] = f6[(size_t)pxA * 13 + c];
        xx6B[c] = f6[(size_t)pxA * 13 + 13 + c];
    }
#pragma unroll
    for (int c = 0; c < 9; ++c) {
        float2 v = *(const float2*)(yyws + (size_t)c * NPX + pxA);
        yy4A[c] = v.x; yy4B[c] = v.y;
    }
#pragma unroll
    for (int c = 0; c < 13; ++c) {
        float2 v = *(const float2*)(yyws + (size_t)(9 + c) * NPX + pxA);
        yy6A[c] = v.x; yy6B[c] = v.y;
    }

    float oA[9], oB[9];
    tp_one<0, 9>(tpws, xx4A, xx6A, yy4A, yy6A, oA);
    tp_one<0, 9>(tpws, xx4B, xx6B, yy4B, yy6B, oB);

    // LDS transpose -> contiguous float4 stores (512 px per block)
#pragma unroll
    for (int c = 0; c < 9; ++c) {
        lds[(2 * tid) * 9 + c] = oA[c];
        lds[(2 * tid + 1) * 9 + c] = oB[c];
    }
    __syncthreads();
    float4* dst = (float4*)(dout + (size_t)blockIdx.x * (512 * 9));
    const float4* src = (const float4*)lds;
#pragma unroll
    for (int k = 0; k < 5; ++k) {
        int i = tid + k * 256;
        if (i < 1152) dst[i] = src[i];
    }
}

// ---------------------------------------------------------------------------
// Kernel K2: o6 only, 2 px/thread.
// ---------------------------------------------------------------------------
__global__ void __launch_bounds__(256)
tp_o6_kernel(const float* __restrict__ f4,
             const float* __restrict__ f6,
             const float* __restrict__ yyws,
             const float* __restrict__ tpw,
             float* __restrict__ dout) {
    __shared__ float lds[512 * 13];
    const int tid = threadIdx.x;
    const int gid = blockIdx.x * 256 + tid;
    const int pxA = gid * 2;

    float tpws[8];
#pragma unroll
    for (int k = 0; k < 8; ++k) tpws[k] = tpw[k];

    float xx4A[9], xx4B[9], xx6A[13], xx6B[13];
    float yy4A[9], yy4B[9], yy6A[13], yy6B[13];
#pragma unroll
    for (int c = 0; c < 9; ++c) {
        xx4A[c] = f4[(size_t)pxA * 9 + c];
        xx4B[c] = f4[(size_t)pxA * 9 + 9 + c];
    }
#pragma unroll
    for (int c = 0; c < 13; ++c) {
        xx6A[c] = f6[(size_t)pxA * 13 + c];
        xx6B[c] = f6[(size_t)pxA * 13 + 13 + c];
    }
#pragma unroll
    for (int c = 0; c < 9; ++c) {
        float2 v = *(const float2*)(yyws + (size_t)c * NPX + pxA);
        yy4A[c] = v.x; yy4B[c] = v.y;
    }
#pragma unroll
    for (int c = 0; c < 13; ++c) {
        float2 v = *(const float2*)(yyws + (size_t)(9 + c) * NPX + pxA);
        yy6A[c] = v.x; yy6B[c] = v.y;
    }

    float oA[13], oB[13];
    tp_one<1, 13>(tpws, xx4A, xx6A, yy4A, yy6A, oA);
    tp_one<1, 13>(tpws, xx4B, xx6B, yy4B, yy6B, oB);

#pragma unroll
    for (int c = 0; c < 13; ++c) {
        lds[(2 * tid) * 13 + c] = oA[c];
        lds[(2 * tid + 1) * 13 + c] = oB[c];
    }
    __syncthreads();
    float4* dst = (float4*)(dout + OUT1OFF + (size_t)blockIdx.x * (512 * 13));
    const float4* src = (const float4*)lds;
#pragma unroll
    for (int k = 0; k < 7; ++k) {
        int i = tid + k * 256;
        if (i < 1664) dst[i] = src[i];
    }
}

// ---------------------------------------------------------------------------
// Fallback fused kernel — used only if ws is too small.
// ---------------------------------------------------------------------------
DEV_INLINE void tp_body(const float (&tpws)[8],
                        const float (&xx4)[9], const float (&xx6)[13],
                        const float (&yy4)[9], const float (&yy6)[13],
                        float (&o4)[9], float (&o6)[13]) {
#pragma unroll
    for (int c = 0; c < 9; ++c)  o4[c] = xx4[c];
#pragma unroll
    for (int c = 0; c < 13; ++c) o6[c] = xx6[c];
    TPG<GB[0], GB[1], 9, 9>::run(tpws[0], tpws[1], xx4, yy4, o4, o6);
    TPG<GB[1], GB[2], 13, 9>::run(tpws[4], tpws[5], xx6, yy4, o4, o6);
    TPG<GB[2], GB[3], 9, 13>::run(tpws[2], tpws[3], xx4, yy6, o4, o6);
    TPG<GB[3], GB[4], 13, 13>::run(tpws[6], tpws[7], xx6, yy6, o4, o6);
}

__global__ void __launch_bounds__(256)
eq_conv_tp_fused(const float* __restrict__ f4,
                 const float* __restrict__ f6,
                 const float* __restrict__ sw,
                 const float* __restrict__ tpw,
                 float* __restrict__ dout) {
    __shared__ __align__(16) float ldsA[6 * RA];
    __shared__ __align__(16) float ldsB[6 * RB];
    const int tid = threadIdx.x;
    const int b  = blockIdx.x >> 10;
    const int t  = blockIdx.x & 1023;
    const int y0 = (t >> 3) * 4;
    const int x0 = (t & 7) * 64;

    const float* f4b = f4 + (size_t)b * (HWN * 9);
    const float* f6b = f6 + (size_t)b * (HWN * 13);

    float wv[9];
#pragma unroll
    for (int k = 0; k < 9; ++k) wv[k] = sw[k];
    float tpws[8];
#pragma unroll
    for (int k = 0; k < 8; ++k) tpws[k] = tpw[k];

    {
        const float4* f4v = (const float4*)f4b;
        const float4* f6v = (const float4*)f6b;
        float4* lAv = (float4*)ldsA;
        float4* lBv = (float4*)ldsB;
        const int xoA = (x0 * 9) >> 2;
        const int xoB = (x0 * 13) >> 2;
        for (int k = tid; k < 6 * (144 + 208); k += 256) {
            if (k < 6 * 144) {
                int r = k / 144, o = k - r * 144;
                int gy = y0 - 1 + r;
                gy = gy < 0 ? 0 : (gy > HH - 1 ? HH - 1 : gy);
                lAv[r * (RA / 4) + o] = f4v[(size_t)gy * 1152 + xoA + o];
            } else {
                int k2 = k - 6 * 144;
                int r = k2 / 208, o = k2 - r * 208;
                int gy = y0 - 1 + r;
                gy = gy < 0 ? 0 : (gy > HH - 1 ? HH - 1 : gy);
                lBv[r * (RB / 4) + o] = f6v[(size_t)gy * 1664 + xoB + o];
            }
        }
        for (int u2 = tid; u2 < 264; u2 += 256) {
            int side = u2 >= 132;
            int u = u2 - side * 132;
            int r = u / 22, c = u - r * 22;
            int gx = side ? (x0 + 64 > WW - 1 ? WW - 1 : x0 + 64)
                          : (x0 - 1 < 0 ? 0 : x0 - 1);
            int gy = y0 - 1 + r;
            gy = gy < 0 ? 0 : (gy > HH - 1 ? HH - 1 : gy);
            if (c < 9)
                ldsA[r * RA + (side ? 585 : 576) + c] =
                    f4b[(size_t)gy * 4608 + gx * 9 + c];
            else
                ldsB[r * RB + (side ? 845 : 832) + (c - 9)] =
                    f6b[(size_t)gy * 6656 + gx * 13 + (c - 9)];
        }
    }
    __syncthreads();

    const int tx = tid & 63, ty = tid >> 6;
    const int aLA = (tx == 0) ? 576 : (tx - 1) * 9;
    const int aMA = tx * 9;
    const int aRA_ = (tx == 63) ? 585 : (tx + 1) * 9;
    const int aLB = (tx == 0) ? 832 : (tx - 1) * 13;
    const int aMB = tx * 13;
    const int aRB_ = (tx == 63) ? 845 : (tx + 1) * 13;

    const float* pAL = ldsA + ty * RA + aLA;
    const float* pAM = ldsA + ty * RA + aMA;
    const float* pAR = ldsA + ty * RA + aRA_;
    const float* pBL = ldsB + ty * RB + aLB;
    const float* pBM = ldsB + ty * RB + aMB;
    const float* pBR = ldsB + ty * RB + aRB_;

    float xx4[9], xx6[13], yy4[9], yy6[13];
#pragma unroll
    for (int c = 0; c < 9; ++c) {
        xx4[c] = pAM[RA + c];
        float s = 0.f;
#pragma unroll
        for (int jr = 0; jr < 3; ++jr) {
            s = fmaf(wv[jr * 3 + 0], pAL[jr * RA + c], s);
            s = fmaf(wv[jr * 3 + 1], pAM[jr * RA + c], s);
            s = fmaf(wv[jr * 3 + 2], pAR[jr * RA + c], s);
        }
        yy4[c] = s;
    }
#pragma unroll
    for (int c = 0; c < 13; ++c) {
        xx6[c] = pBM[RB + c];
        float s = 0.f;
#pragma unroll
        for (int jr = 0; jr < 3; ++jr) {
            s = fmaf(wv[jr * 3 + 0], pBL[jr * RB + c], s);
            s = fmaf(wv[jr * 3 + 1], pBM[jr * RB + c], s);
            s = fmaf(wv[jr * 3 + 2], pBR[jr * RB + c], s);
        }
        yy6[c] = s;
    }

    float o4[9], o6[13];
    tp_body(tpws, xx4, xx6, yy4, yy6, o4, o6);

    const int pos = b * HWN + (y0 + ty) * WW + (x0 + tx);
    float* o4p = dout + (size_t)pos * 9;
    float* o6p = dout + OUT1OFF + (size_t)pos * 13;
#pragma unroll
    for (int c = 0; c < 9; ++c)  o4p[c] = o4[c];
#pragma unroll
    for (int c = 0; c < 13; ++c) o6p[c] = o6[c];
}

extern "C" void kernel_launch(void* const* d_in, const int* in_sizes, int n_in,
                              void* d_out, int out_size, void* d_ws, size_t ws_size,
                              hipStream_t stream) {
    const float* f4  = (const float*)d_in[0];
    const float* f6  = (const float*)d_in[1];
    const float* sw  = (const float*)d_in[2];
    const float* tpw = (const float*)d_in[3];
    float* out = (float*)d_out;

    const size_t plane = (size_t)NPX * sizeof(float);
    const size_t need = 22 * plane;              // yy planes, ~92 MB

    if (ws_size >= need) {
        float* yyws = (float*)d_ws;
        hipLaunchKernelGGL(conv_yy_kernel,
                           dim3(BB * (HH / 4) * (WW / 64)), dim3(256), 0, stream,
                           f4, f6, sw, yyws);
        hipLaunchKernelGGL(tp_o4_kernel,
                           dim3(NPX / 512), dim3(256), 0, stream,
                           f4, f6, yyws, tpw, out);
        hipLaunchKernelGGL(tp_o6_kernel,
                           dim3(NPX / 512), dim3(256), 0, stream,
                           f4, f6, yyws, tpw, out);
    } else {
        hipLaunchKernelGGL(eq_conv_tp_fused,
                           dim3(BB * (HH / 4) * (WW / 64)), dim3(256), 0, stream,
                           f4, f6, sw, tpw, out);
    }
}

// Round 15
// 133.467 us; speedup vs baseline: 1.7611x; 1.7611x over previous
//
#include <hip/hip_runtime.h>
#include <array>

#define DEV_INLINE __device__ __forceinline__

// Problem geometry (fixed by setup_inputs)
constexpr int HH = 512, WW = 512, BB = 4;
constexpr int HWN = HH * WW;
constexpr int NPX = BB * HWN;           // 1,048,576 pixels
constexpr int OUT1OFF = NPX * 9;        // d_out: [B*HW*9] then [B*HW*13]

// ---------------------------------------------------------------------------
// Compile-time sparse structure of the real Wigner-3j tensors.
// ---------------------------------------------------------------------------
constexpr bool keepE(int u1, int u2, int u3) {
    int a = u1 < 0 ? -u1 : u1, b = u2 < 0 ? -u2 : u2, c = u3 < 0 ? -u3 : u3;
    int neg = (u1 < 0) + (u2 < 0) + (u3 < 0);
    if (neg & 1) return false;
    int d = a > b ? a - b : b - a;
    return (c == a + b) || (c == d);
}

struct Ent { unsigned char xi, yi, oi, p; };

// Group order: (4,4), (6,4), (4,6), (6,6)
constexpr int GRP[4][2] = {{4,4},{6,4},{4,6},{6,6}};

constexpr int countEnt() {
    int n = 0;
    for (int g = 0; g < 4; ++g) {
        int l1 = GRP[g][0], l2 = GRP[g][1];
        for (int u1 = -l1; u1 <= l1; ++u1)
            for (int u2 = -l2; u2 <= l2; ++u2)
                for (int t3 = 0; t3 < 2; ++t3) {
                    int l3 = t3 ? 6 : 4;
                    for (int u3 = -l3; u3 <= l3; ++u3)
                        if (keepE(u1, u2, u3)) ++n;
                }
    }
    return n;
}
constexpr int NTOT = countEnt();
static_assert(NTOT > 0 && NTOT < 4096, "entry count sanity");

constexpr std::array<Ent, NTOT> makeTab() {
    std::array<Ent, NTOT> T{};
    int n = 0;
    for (int g = 0; g < 4; ++g) {
        int l1 = GRP[g][0], l2 = GRP[g][1];
        int xo = (l1 == 6) ? 9 : 0, yo = (l2 == 6) ? 9 : 0;
        for (int u1 = -l1; u1 <= l1; ++u1)
            for (int u2 = -l2; u2 <= l2; ++u2)
                for (int t3 = 0; t3 < 2; ++t3) {
                    int l3 = t3 ? 6 : 4;
                    int oo = (l3 == 6) ? 9 : 0;
                    for (int u3 = -l3; u3 <= l3; ++u3)
                        if (keepE(u1, u2, u3)) {
                            T[n].xi = (unsigned char)(xo + l1 + u1);
                            T[n].yi = (unsigned char)(yo + l2 + u2);
                            T[n].oi = (unsigned char)(oo + l3 + u3);
                            T[n].p  = (unsigned char)(((l1 == 6) ? 4 : 0) |
                                                      ((l2 == 6) ? 2 : 0) |
                                                      ((l3 == 6) ? 1 : 0));
                            ++n;
                        }
                }
    }
    return T;
}
constexpr auto TAB = makeTab();

struct Run { unsigned short e0; unsigned char xi, yi, n; };

constexpr int countRuns() {
    int n = 0;
    for (int e = 0; e < NTOT; ) {
        int j = e;
        while (j < NTOT && TAB[j].xi == TAB[e].xi && TAB[j].yi == TAB[e].yi) ++j;
        ++n; e = j;
    }
    return n;
}
constexpr int NRUN = countRuns();

constexpr std::array<Run, NRUN> makeRuns() {
    std::array<Run, NRUN> R{};
    int n = 0;
    for (int e = 0; e < NTOT; ) {
        int j = e;
        while (j < NTOT && TAB[j].xi == TAB[e].xi && TAB[j].yi == TAB[e].yi) ++j;
        R[n].e0 = (unsigned short)e;
        R[n].xi = TAB[e].xi;
        R[n].yi = TAB[e].yi;
        R[n].n  = (unsigned char)(j - e);
        ++n; e = j;
    }
    return R;
}
constexpr auto RUNS = makeRuns();

constexpr int grpPos(int pp) { return pp == 0 ? 0 : (pp == 2 ? 1 : (pp == 1 ? 2 : 3)); }
constexpr std::array<int, 5> makeGB() {
    std::array<int, 5> G{};
    G[0] = 0;
    int g = 0;
    for (int r = 0; r < NRUN; ++r) {
        int gp = grpPos(TAB[RUNS[r].e0].p >> 1);
        while (g < gp) { ++g; G[g] = r; }
    }
    while (g < 4) { ++g; G[g] = NRUN; }
    G[4] = NRUN;
    return G;
}
constexpr auto GB = makeGB();
static_assert(GB[4] == NRUN, "GB sanity");

// Per-run / per-entry output-selection helpers (SEL=0 -> o4, SEL=1 -> o6).
constexpr bool entSel(int e, int SEL) {
    return SEL ? (TAB[e].oi >= 9) : (TAB[e].oi < 9);
}
constexpr int runCount(int r, int SEL) {
    int c = 0;
    for (int e = RUNS[r].e0; e < RUNS[r].e0 + RUNS[r].n; ++e)
        if (entSel(e, SEL)) ++c;
    return c;
}

// ---------------------------------------------------------------------------
// Compile-time Wigner-3j values (fp64 constexpr, Newton csqrt).
// ---------------------------------------------------------------------------
constexpr std::array<double, 20> makeFact() {
    std::array<double, 20> F{};
    F[0] = 1.0;
    for (int i = 1; i < 20; ++i) F[i] = F[i - 1] * (double)i;
    return F;
}
constexpr auto FACT = makeFact();

constexpr double csqrt(double x) {
    if (x <= 0.0) return 0.0;
    double g = x > 1.0 ? x : 1.0, prev = 0.0;
    for (int i = 0; i < 200 && g != prev; ++i) { prev = g; g = 0.5 * (g + x / g); }
    return g;
}

constexpr double su2cg(int j1, int j2, int j3, int m1, int m2, int m3) {
    int vmin = -j1 + j2 + m3;
    if (-j1 + m1 > vmin) vmin = -j1 + m1;
    if (vmin < 0) vmin = 0;
    int vmax = j2 + j3 + m1;
    { int t = j3 - j1 + j2; if (t < vmax) vmax = t; t = j3 + m3; if (t < vmax) vmax = t; }
    double num = FACT[j3 + j1 - j2] * FACT[j3 - j1 + j2] * FACT[j1 + j2 - j3] *
                 FACT[j3 + m3] * FACT[j3 - m3];
    double den = FACT[j1 + j2 + j3 + 1] * FACT[j1 - m1] * FACT[j1 + m1] *
                 FACT[j2 - m2] * FACT[j2 + m2];
    double C = csqrt((2.0 * j3 + 1.0) * num / den);
    double S = 0.0;
    for (int v = vmin; v <= vmax; ++v) {
        double t = (FACT[j2 + j3 + m1 - v] * FACT[j1 - m1 + v]) /
                   (FACT[v] * FACT[j3 - j1 + j2 - v] * FACT[j3 + m3 - v] *
                    FACT[v + j1 - j2 - m3]);
        S += ((v + j2 + m2) & 1) ? -t : t;
    }
    return C * S;
}

struct Cplx { double re, im; };

constexpr Cplx qent(int l, int r, int c) {
    const double s2 = 0.70710678118654752440;
    if (c == r) {
        if (r < l)  return {0.0, -s2};
        if (r == l) return {1.0, 0.0};
        return {((r - l) & 1) ? -s2 : s2, 0.0};
    }
    if (r < l) return {s2, 0.0};
    return {0.0, ((r - l) & 1) ? -s2 : s2};
}

constexpr double rawval(int e) {
    Ent E = TAB[e];
    int l1 = (E.p & 4) ? 6 : 4, l2 = (E.p & 2) ? 6 : 4, l3 = (E.p & 1) ? 6 : 4;
    int j = E.xi - ((l1 == 6) ? 9 : 0);
    int L = E.yi - ((l2 == 6) ? 9 : 0);
    int m = E.oi - ((l3 == 6) ? 9 : 0);
    double acc = 0.0;
    for (int a = 0; a < 2; ++a) {
        int i = a ? (2 * l1 - j) : j;
        if (a && i == j) continue;
        Cplx q1 = qent(l1, i, j);
        for (int b = 0; b < 2; ++b) {
            int k = b ? (2 * l2 - L) : L;
            if (b && k == L) continue;
            Cplx q2 = qent(l2, k, L);
            int m1 = i - l1, m2 = k - l2;
            int n = m1 + m2 + l3;
            if (n < 0 || n > 2 * l3) continue;
            if (n != m && n != 2 * l3 - m) continue;
            Cplx q3 = qent(l3, n, m);
            double cg = su2cg(l1, l2, l3, m1, m2, n - l3);
            double Ar = q1.re * q2.re - q1.im * q2.im;
            double Ai = q1.re * q2.im + q1.im * q2.re;
            acc += (Ar * q3.re + Ai * q3.im) * cg;
        }
    }
    int s = 1;
    if (l1 == 6) s = -s;
    if (l2 == 6) s = -s;
    if (l3 == 6) s = -s;
    return s < 0 ? -acc : acc;
}

// Frobenius norms per path — chunked constexpr evaluations.
constexpr int NCH = 16;
constexpr int CHSZ = (NTOT + NCH - 1) / NCH;

template<int C>
constexpr std::array<double, 8> frobChunk() {
    std::array<double, 8> s{};
    for (int i = 0; i < CHSZ; ++i) {
        int e = C * CHSZ + i;
        if (e < NTOT) { double r = rawval(e); s[TAB[e].p] += r * r; }
    }
    return s;
}
constexpr auto FR0  = frobChunk<0>();   constexpr auto FR1  = frobChunk<1>();
constexpr auto FR2  = frobChunk<2>();   constexpr auto FR3  = frobChunk<3>();
constexpr auto FR4  = frobChunk<4>();   constexpr auto FR5  = frobChunk<5>();
constexpr auto FR6  = frobChunk<6>();   constexpr auto FR7  = frobChunk<7>();
constexpr auto FR8  = frobChunk<8>();   constexpr auto FR9  = frobChunk<9>();
constexpr auto FR10 = frobChunk<10>();  constexpr auto FR11 = frobChunk<11>();
constexpr auto FR12 = frobChunk<12>();  constexpr auto FR13 = frobChunk<13>();
constexpr auto FR14 = frobChunk<14>();  constexpr auto FR15 = frobChunk<15>();

constexpr std::array<double, 8> makeFrob() {
    std::array<double, 8> s{};
    const std::array<double, 8>* parts[NCH] = {
        &FR0,&FR1,&FR2,&FR3,&FR4,&FR5,&FR6,&FR7,
        &FR8,&FR9,&FR10,&FR11,&FR12,&FR13,&FR14,&FR15};
    for (int c = 0; c < NCH; ++c)
        for (int p = 0; p < 8; ++p) s[p] += (*parts[c])[p];
    for (int p = 0; p < 8; ++p) s[p] = csqrt(s[p]);
    return s;
}
constexpr auto FROB = makeFrob();

// Per-entry final coefficient — inline literal.
template<int E>
struct CofV {
    static constexpr int    P  = TAB[E].p;
    static constexpr double PW = 0.5 * ((P & 1) ? 3.60555127546398929312 /*sqrt13*/
                                               : 3.0 /*sqrt9*/);
    static constexpr float  v  = (float)(rawval(E) * PW / FROB[P]);
};

// ---------------------------------------------------------------------------
// Output-filtered force-unrolled TP (SEL=0 -> o4[9], SEL=1 -> o6[13]).
// ---------------------------------------------------------------------------
template<int E, int N, int SEL, int ON>
struct FChain {
    static DEV_INLINE void run(float pr, float (&o)[ON]) {
        if constexpr (entSel(E, SEL)) {
            constexpr int oi = SEL ? TAB[E].oi - 9 : TAB[E].oi;
            constexpr float kc = CofV<E>::v;
            o[oi] = fmaf(kc, pr, o[oi]);
        }
        if constexpr (N > 1) FChain<E + 1, N - 1, SEL, ON>::run(pr, o);
    }
};

template<int LO, int HI, int XN, int YN, int SEL, int ON>
struct TPGF {
    static DEV_INLINE void run(float s, const float (&xs)[XN],
                               const float (&ys)[YN], float (&o)[ON]) {
        if constexpr (HI - LO == 1) {
            if constexpr (runCount(LO, SEL) > 0) {
                constexpr Run R = RUNS[LO];
                constexpr int xil = R.xi >= 9 ? R.xi - 9 : R.xi;
                constexpr int yil = R.yi >= 9 ? R.yi - 9 : R.yi;
                float pr = xs[xil] * ys[yil] * s;
                FChain<R.e0, R.n, SEL, ON>::run(pr, o);
            }
        } else {
            constexpr int MID = LO + (HI - LO) / 2;
            TPGF<LO, MID, XN, YN, SEL, ON>::run(s, xs, ys, o);
            TPGF<MID, HI, XN, YN, SEL, ON>::run(s, xs, ys, o);
        }
    }
};

// One pixel's output-filtered TP (+ residual init).
template<int SEL, int ON>
DEV_INLINE void tp_one(const float (&tpws)[8],
                       const float (&xx4)[9], const float (&xx6)[13],
                       const float (&yy4)[9], const float (&yy6)[13],
                       float (&o)[ON]) {
    if constexpr (SEL == 0) {
#pragma unroll
        for (int c = 0; c < 9; ++c) o[c] = xx4[c];
    } else {
#pragma unroll
        for (int c = 0; c < 13; ++c) o[c] = xx6[c];
    }
    TPGF<GB[0], GB[1], 9, 9, SEL, ON>::run(tpws[SEL ? 1 : 0], xx4, yy4, o);
    TPGF<GB[1], GB[2], 13, 9, SEL, ON>::run(tpws[SEL ? 5 : 4], xx6, yy4, o);
    TPGF<GB[2], GB[3], 9, 13, SEL, ON>::run(tpws[SEL ? 3 : 2], xx4, yy6, o);
    TPGF<GB[3], GB[4], 13, 13, SEL, ON>::run(tpws[SEL ? 7 : 6], xx6, yy6, o);
}

// Unfiltered full TP (fused fallback only).
template<int E, int N>
struct AccChain {
    static DEV_INLINE void run(float pr4, float pr6,
                               float (&o4)[9], float (&o6)[13]) {
        constexpr int oi = TAB[E].oi;
        constexpr float kc = CofV<E>::v;
        if constexpr (oi < 9) o4[oi] = fmaf(kc, pr4, o4[oi]);
        else                  o6[oi - 9] = fmaf(kc, pr6, o6[oi - 9]);
        if constexpr (N > 1) AccChain<E + 1, N - 1>::run(pr4, pr6, o4, o6);
    }
};

template<int LO, int HI, int XN, int YN>
struct TPG {
    static DEV_INLINE void run(float s4, float s6,
                               const float (&xs)[XN], const float (&ys)[YN],
                               float (&o4)[9], float (&o6)[13]) {
        if constexpr (HI - LO == 1) {
            constexpr Run R = RUNS[LO];
            constexpr int xil = R.xi >= 9 ? R.xi - 9 : R.xi;
            constexpr int yil = R.yi >= 9 ? R.yi - 9 : R.yi;
            constexpr bool has4 = (TAB[R.e0].p & 1) == 0;
            constexpr bool has6 = (TAB[R.e0 + R.n - 1].p & 1) == 1;
            float pr = xs[xil] * ys[yil];
            float pr4 = 0.f, pr6 = 0.f;
            if constexpr (has4) pr4 = pr * s4;
            if constexpr (has6) pr6 = pr * s6;
            AccChain<R.e0, R.n>::run(pr4, pr6, o4, o6);
        } else {
            constexpr int MID = LO + (HI - LO) / 2;
            TPG<LO, MID, XN, YN>::run(s4, s6, xs, ys, o4, o6);
            TPG<MID, HI, XN, YN>::run(s4, s6, xs, ys, o4, o6);
        }
    }
};

// ---------------------------------------------------------------------------
// Kernel A: 3x3 conv -> yy planes (SoA) in d_ws. (R9/R13 proven path.)
// ---------------------------------------------------------------------------
constexpr int RA = 596, RB = 860;

__global__ void __launch_bounds__(256)
conv_yy_kernel(const float* __restrict__ f4,
               const float* __restrict__ f6,
               const float* __restrict__ sw,
               float* __restrict__ yyws) {
    __shared__ __align__(16) float ldsA[6 * RA];
    __shared__ __align__(16) float ldsB[6 * RB];
    const int tid = threadIdx.x;
    const int b  = blockIdx.x >> 10;
    const int t  = blockIdx.x & 1023;
    const int y0 = (t >> 3) * 4;
    const int x0 = (t & 7) * 64;

    const float* f4b = f4 + (size_t)b * (HWN * 9);
    const float* f6b = f6 + (size_t)b * (HWN * 13);

    float wv[9];
#pragma unroll
    for (int k = 0; k < 9; ++k) wv[k] = sw[k];

    {
        const float4* f4v = (const float4*)f4b;
        const float4* f6v = (const float4*)f6b;
        float4* lAv = (float4*)ldsA;
        float4* lBv = (float4*)ldsB;
        const int xoA = (x0 * 9) >> 2;
        const int xoB = (x0 * 13) >> 2;
        for (int k = tid; k < 6 * (144 + 208); k += 256) {
            if (k < 6 * 144) {
                int r = k / 144, o = k - r * 144;
                int gy = y0 - 1 + r;
                gy = gy < 0 ? 0 : (gy > HH - 1 ? HH - 1 : gy);
                lAv[r * (RA / 4) + o] = f4v[(size_t)gy * 1152 + xoA + o];
            } else {
                int k2 = k - 6 * 144;
                int r = k2 / 208, o = k2 - r * 208;
                int gy = y0 - 1 + r;
                gy = gy < 0 ? 0 : (gy > HH - 1 ? HH - 1 : gy);
                lBv[r * (RB / 4) + o] = f6v[(size_t)gy * 1664 + xoB + o];
            }
        }
        for (int u2 = tid; u2 < 264; u2 += 256) {
            int side = u2 >= 132;
            int u = u2 - side * 132;
            int r = u / 22, c = u - r * 22;
            int gx = side ? (x0 + 64 > WW - 1 ? WW - 1 : x0 + 64)
                          : (x0 - 1 < 0 ? 0 : x0 - 1);
            int gy = y0 - 1 + r;
            gy = gy < 0 ? 0 : (gy > HH - 1 ? HH - 1 : gy);
            if (c < 9)
                ldsA[r * RA + (side ? 585 : 576) + c] =
                    f4b[(size_t)gy * 4608 + gx * 9 + c];
            else
                ldsB[r * RB + (side ? 845 : 832) + (c - 9)] =
                    f6b[(size_t)gy * 6656 + gx * 13 + (c - 9)];
        }
    }
    __syncthreads();

    const int tx = tid & 63, ty = tid >> 6;

    const int aLA = (tx == 0) ? 576 : (tx - 1) * 9;
    const int aMA = tx * 9;
    const int aRA_ = (tx == 63) ? 585 : (tx + 1) * 9;
    const int aLB = (tx == 0) ? 832 : (tx - 1) * 13;
    const int aMB = tx * 13;
    const int aRB_ = (tx == 63) ? 845 : (tx + 1) * 13;

    const float* pAL = ldsA + ty * RA + aLA;
    const float* pAM = ldsA + ty * RA + aMA;
    const float* pAR = ldsA + ty * RA + aRA_;
    const float* pBL = ldsB + ty * RB + aLB;
    const float* pBM = ldsB + ty * RB + aMB;
    const float* pBR = ldsB + ty * RB + aRB_;

    const int pos = b * HWN + (y0 + ty) * WW + (x0 + tx);

#pragma unroll
    for (int c = 0; c < 9; ++c) {
        float s = 0.f;
#pragma unroll
        for (int jr = 0; jr < 3; ++jr) {
            s = fmaf(wv[jr * 3 + 0], pAL[jr * RA + c], s);
            s = fmaf(wv[jr * 3 + 1], pAM[jr * RA + c], s);
            s = fmaf(wv[jr * 3 + 2], pAR[jr * RA + c], s);
        }
        yyws[(size_t)c * NPX + pos] = s;
    }
#pragma unroll
    for (int c = 0; c < 13; ++c) {
        float s = 0.f;
#pragma unroll
        for (int jr = 0; jr < 3; ++jr) {
            s = fmaf(wv[jr * 3 + 0], pBL[jr * RB + c], s);
            s = fmaf(wv[jr * 3 + 1], pBM[jr * RB + c], s);
            s = fmaf(wv[jr * 3 + 2], pBR[jr * RB + c], s);
        }
        yyws[(size_t)(9 + c) * NPX + pos] = s;
    }
}

// ---------------------------------------------------------------------------
// Merged TP kernel: blocks [0, NB) do o4, blocks [NB, 2*NB) do o6.
// Per-path code identical to R13's tp_o4/tp_o6 (1 px/thread, ~104 VGPR).
// Merging removes the inter-kernel drain so o4 tail overlaps o6 head.
// ---------------------------------------------------------------------------
DEV_INLINE void tp_o4_body(int px0, int tid,
                           const float* __restrict__ f4,
                           const float* __restrict__ f6,
                           const float* __restrict__ yyws,
                           const float (&tpws)[8],
                           float* __restrict__ dout,
                           float* lds) {
    const int px = px0 + tid;

    float xx4[9], xx6[13], yy4[9], yy6[13];
#pragma unroll
    for (int c = 0; c < 9; ++c)  xx4[c] = f4[(size_t)px * 9 + c];
#pragma unroll
    for (int c = 0; c < 13; ++c) xx6[c] = f6[(size_t)px * 13 + c];
#pragma unroll
    for (int c = 0; c < 9; ++c)  yy4[c] = yyws[(size_t)c * NPX + px];
#pragma unroll
    for (int c = 0; c < 13; ++c) yy6[c] = yyws[(size_t)(9 + c) * NPX + px];

    float o4[9];
    tp_one<0, 9>(tpws, xx4, xx6, yy4, yy6, o4);

#pragma unroll
    for (int c = 0; c < 9; ++c) lds[tid * 9 + c] = o4[c];
    __syncthreads();
    float4* dst = (float4*)(dout + (size_t)px0 * 9);
    const float4* src = (const float4*)lds;
#pragma unroll
    for (int k = 0; k < 3; ++k) {
        int i = tid + k * 256;
        if (i < 576) dst[i] = src[i];
    }
}

DEV_INLINE void tp_o6_body(int px0, int tid,
                           const float* __restrict__ f4,
                           const float* __restrict__ f6,
                           const float* __restrict__ yyws,
                           const float (&tpws)[8],
                           float* __restrict__ dout,
                           float* lds) {
    const int px = px0 + tid;

    float xx4[9], xx6[13], yy4[9], yy6[13];
#pragma unroll
    for (int c = 0; c < 9; ++c)  xx4[c] = f4[(size_t)px * 9 + c];
#pragma unroll
    for (int c = 0; c < 13; ++c) xx6[c] = f6[(size_t)px * 13 + c];
#pragma unroll
    for (int c = 0; c < 9; ++c)  yy4[c] = yyws[(size_t)c * NPX + px];
#pragma unroll
    for (int c = 0; c < 13; ++c) yy6[c] = yyws[(size_t)(9 + c) * NPX + px];

    float o6[13];
    tp_one<1, 13>(tpws, xx4, xx6, yy4, yy6, o6);

#pragma unroll
    for (int c = 0; c < 13; ++c) lds[tid * 13 + c] = o6[c];
    __syncthreads();
    float4* dst = (float4*)(dout + OUT1OFF + (size_t)px0 * 13);
    const float4* src = (const float4*)lds;
#pragma unroll
    for (int k = 0; k < 4; ++k) {
        int i = tid + k * 256;
        if (i < 832) dst[i] = src[i];
    }
}

constexpr int NBTP = NPX / 256;          // 4096 blocks per output half

__global__ void __launch_bounds__(256)
tp_both_kernel(const float* __restrict__ f4,
               const float* __restrict__ f6,
               const float* __restrict__ yyws,
               const float* __restrict__ tpw,
               float* __restrict__ dout) {
    __shared__ float lds[3328];          // max(256*9, 256*13)
    const int tid = threadIdx.x;

    float tpws[8];
#pragma unroll
    for (int k = 0; k < 8; ++k) tpws[k] = tpw[k];

    if (blockIdx.x < NBTP) {
        tp_o4_body(blockIdx.x * 256, tid, f4, f6, yyws, tpws, dout, lds);
    } else {
        tp_o6_body((blockIdx.x - NBTP) * 256, tid, f4, f6, yyws, tpws, dout, lds);
    }
}

// ---------------------------------------------------------------------------
// Fallback fused kernel — used only if ws is too small.
// ---------------------------------------------------------------------------
DEV_INLINE void tp_body(const float (&tpws)[8],
                        const float (&xx4)[9], const float (&xx6)[13],
                        const float (&yy4)[9], const float (&yy6)[13],
                        float (&o4)[9], float (&o6)[13]) {
#pragma unroll
    for (int c = 0; c < 9; ++c)  o4[c] = xx4[c];
#pragma unroll
    for (int c = 0; c < 13; ++c) o6[c] = xx6[c];
    TPG<GB[0], GB[1], 9, 9>::run(tpws[0], tpws[1], xx4, yy4, o4, o6);
    TPG<GB[1], GB[2], 13, 9>::run(tpws[4], tpws[5], xx6, yy4, o4, o6);
    TPG<GB[2], GB[3], 9, 13>::run(tpws[2], tpws[3], xx4, yy6, o4, o6);
    TPG<GB[3], GB[4], 13, 13>::run(tpws[6], tpws[7], xx6, yy6, o4, o6);
}

__global__ void __launch_bounds__(256)
eq_conv_tp_fused(const float* __restrict__ f4,
                 const float* __restrict__ f6,
                 const float* __restrict__ sw,
                 const float* __restrict__ tpw,
                 float* __restrict__ dout) {
    __shared__ __align__(16) float ldsA[6 * RA];
    __shared__ __align__(16) float ldsB[6 * RB];
    const int tid = threadIdx.x;
    const int b  = blockIdx.x >> 10;
    const int t  = blockIdx.x & 1023;
    const int y0 = (t >> 3) * 4;
    const int x0 = (t & 7) * 64;

    const float* f4b = f4 + (size_t)b * (HWN * 9);
    const float* f6b = f6 + (size_t)b * (HWN * 13);

    float wv[9];
#pragma unroll
    for (int k = 0; k < 9; ++k) wv[k] = sw[k];
    float tpws[8];
#pragma unroll
    for (int k = 0; k < 8; ++k) tpws[k] = tpw[k];

    {
        const float4* f4v = (const float4*)f4b;
        const float4* f6v = (const float4*)f6b;
        float4* lAv = (float4*)ldsA;
        float4* lBv = (float4*)ldsB;
        const int xoA = (x0 * 9) >> 2;
        const int xoB = (x0 * 13) >> 2;
        for (int k = tid; k < 6 * (144 + 208); k += 256) {
            if (k < 6 * 144) {
                int r = k / 144, o = k - r * 144;
                int gy = y0 - 1 + r;
                gy = gy < 0 ? 0 : (gy > HH - 1 ? HH - 1 : gy);
                lAv[r * (RA / 4) + o] = f4v[(size_t)gy * 1152 + xoA + o];
            } else {
                int k2 = k - 6 * 144;
                int r = k2 / 208, o = k2 - r * 208;
                int gy = y0 - 1 + r;
                gy = gy < 0 ? 0 : (gy > HH - 1 ? HH - 1 : gy);
                lBv[r * (RB / 4) + o] = f6v[(size_t)gy * 1664 + xoB + o];
            }
        }
        for (int u2 = tid; u2 < 264; u2 += 256) {
            int side = u2 >= 132;
            int u = u2 - side * 132;
            int r = u / 22, c = u - r * 22;
            int gx = side ? (x0 + 64 > WW - 1 ? WW - 1 : x0 + 64)
                          : (x0 - 1 < 0 ? 0 : x0 - 1);
            int gy = y0 - 1 + r;
            gy = gy < 0 ? 0 : (gy > HH - 1 ? HH - 1 : gy);
            if (c < 9)
                ldsA[r * RA + (side ? 585 : 576) + c] =
                    f4b[(size_t)gy * 4608 + gx * 9 + c];
            else
                ldsB[r * RB + (side ? 845 : 832) + (c - 9)] =
                    f6b[(size_t)gy * 6656 + gx * 13 + (c - 9)];
        }
    }
    __syncthreads();

    const int tx = tid & 63, ty = tid >> 6;
    const int aLA = (tx == 0) ? 576 : (tx - 1) * 9;
    const int aMA = tx * 9;
    const int aRA_ = (tx == 63) ? 585 : (tx + 1) * 9;
    const int aLB = (tx == 0) ? 832 : (tx - 1) * 13;
    const int aMB = tx * 13;
    const int aRB_ = (tx == 63) ? 845 : (tx + 1) * 13;

    const float* pAL = ldsA + ty * RA + aLA;
    const float* pAM = ldsA + ty * RA + aMA;
    const float* pAR = ldsA + ty * RA + aRA_;
    const float* pBL = ldsB + ty * RB + aLB;
    const float* pBM = ldsB + ty * RB + aMB;
    const float* pBR = ldsB + ty * RB + aRB_;

    float xx4[9], xx6[13], yy4[9], yy6[13];
#pragma unroll
    for (int c = 0; c < 9; ++c) {
        xx4[c] = pAM[RA + c];
        float s = 0.f;
#pragma unroll
        for (int jr = 0; jr < 3; ++jr) {
            s = fmaf(wv[jr * 3 + 0], pAL[jr * RA + c], s);
            s = fmaf(wv[jr * 3 + 1], pAM[jr * RA + c], s);
            s = fmaf(wv[jr * 3 + 2], pAR[jr * RA + c], s);
        }
        yy4[c] = s;
    }
#pragma unroll
    for (int c = 0; c < 13; ++c) {
        xx6[c] = pBM[RB + c];
        float s = 0.f;
#pragma unroll
        for (int jr = 0; jr < 3; ++jr) {
            s = fmaf(wv[jr * 3 + 0], pBL[jr * RB + c], s);
            s = fmaf(wv[jr * 3 + 1], pBM[jr * RB + c], s);
            s = fmaf(wv[jr * 3 + 2], pBR[jr * RB + c], s);
        }
        yy6[c] = s;
    }

    float o4[9], o6[13];
    tp_body(tpws, xx4, xx6, yy4, yy6, o4, o6);

    const int pos = b * HWN + (y0 + ty) * WW + (x0 + tx);
    float* o4p = dout + (size_t)pos * 9;
    float* o6p = dout + OUT1OFF + (size_t)pos * 13;
#pragma unroll
    for (int c = 0; c < 9; ++c)  o4p[c] = o4[c];
#pragma unroll
    for (int c = 0; c < 13; ++c) o6p[c] = o6[c];
}

extern "C" void kernel_launch(void* const* d_in, const int* in_sizes, int n_in,
                              void* d_out, int out_size, void* d_ws, size_t ws_size,
                              hipStream_t stream) {
    const float* f4  = (const float*)d_in[0];
    const float* f6  = (const float*)d_in[1];
    const float* sw  = (const float*)d_in[2];
    const float* tpw = (const float*)d_in[3];
    float* out = (float*)d_out;

    const size_t plane = (size_t)NPX * sizeof(float);
    const size_t need = 22 * plane;              // yy planes, ~92 MB

    if (ws_size >= need) {
        float* yyws = (float*)d_ws;
        hipLaunchKernelGGL(conv_yy_kernel,
                           dim3(BB * (HH / 4) * (WW / 64)), dim3(256), 0, stream,
                           f4, f6, sw, yyws);
        hipLaunchKernelGGL(tp_both_kernel,
                           dim3(2 * NBTP), dim3(256), 0, stream,
                           f4, f6, yyws, tpw, out);
    } else {
        hipLaunchKernelGGL(eq_conv_tp_fused,
                           dim3(BB * (HH / 4) * (WW / 64)), dim3(256), 0, stream,
                           f4, f6, sw, tpw, out);
    }
}